// Round 6
// baseline (306.086 us; speedup 1.0000x reference)
//
#include <hip/hip_runtime.h>
#include <stdint.h>

typedef __attribute__((ext_vector_type(8))) __bf16 bf16x8;
typedef __attribute__((ext_vector_type(4))) float f32x4;
typedef __attribute__((ext_vector_type(4))) short short4v;

// Problem constants
static constexpr int SEQ  = 2048;   // N
static constexpr int DQKV = 3072;   // q(2048) + k(512) + v(512)
static constexpr int HD   = 128;

// round-to-nearest-even fp32 -> bf16 bits
__device__ __forceinline__ short f2bf(float f) {
  unsigned u = __builtin_bit_cast(unsigned, f);
  u += 0x7fffu + ((u >> 16) & 1u);
  return (short)(u >> 16);
}

__device__ __forceinline__ unsigned pack2(float a, float b) {
  return (unsigned)(unsigned short)f2bf(a) | ((unsigned)(unsigned short)f2bf(b) << 16);
}

// async global->LDS, 16B per lane; LDS dest must be wave-uniform base + lane*16
__device__ __forceinline__ void gl_lds16(const void* g, void* l) {
  __builtin_amdgcn_global_load_lds(
      (const __attribute__((address_space(1))) void*)g,
      (__attribute__((address_space(3))) void*)l, 16, 0, 0);
}

// ---------------- fused prep: cast x + transpose-cast all weights ----------------
__global__ __launch_bounds__(256)
void prep_kernel(const float* __restrict__ x, const float* __restrict__ Wq,
                 const float* __restrict__ Wk, const float* __restrict__ Wv,
                 const float* __restrict__ Wo,
                 short* __restrict__ xb, short* __restrict__ WqkvT,
                 short* __restrict__ WoT) {
  int blk = blockIdx.x, tid = threadIdx.x;
  if (blk < 8192) {
    int i = blk * 256 + tid;
    float4 v = reinterpret_cast<const float4*>(x)[i];
    short4v o;
    o[0] = f2bf(v.x); o[1] = f2bf(v.y); o[2] = f2bf(v.z); o[3] = f2bf(v.w);
    *reinterpret_cast<short4v*>(xb + (size_t)i * 4) = o;
    return;
  }
  blk -= 8192;
  __shared__ float tile[32][33];
  const float* in; short* out; int C, bx, by;
  if (blk < 4096)      { in = Wq; out = WqkvT;                     C = 2048; bx = blk & 63; by = blk >> 6; }
  else if (blk < 5120) { int t = blk - 4096; in = Wk; out = WqkvT + (size_t)2048 * 2048; C = 512; bx = t & 15; by = t >> 4; }
  else if (blk < 6144) { int t = blk - 5120; in = Wv; out = WqkvT + (size_t)2560 * 2048; C = 512; bx = t & 15; by = t >> 4; }
  else                 { int t = blk - 6144; in = Wo; out = WoT;   C = 2048; bx = t & 63; by = t >> 6; }
  const int R = 2048;
  int c0 = bx * 32, r0 = by * 32, tx = tid & 31, ty = tid >> 5;
  for (int i = 0; i < 4; i++)
    tile[ty + i * 8][tx] = in[(size_t)(r0 + ty + i * 8) * C + c0 + tx];
  __syncthreads();
  for (int i = 0; i < 4; i++)
    out[(size_t)(c0 + ty + i * 8) * R + r0 + tx] = f2bf(tile[tx][ty + i * 8]);
}

// -------- transpose V section of qkv[4096][3072] -> vT[b*512 + gd][2048] bf16 --------
__global__ __launch_bounds__(256) void transpose_v_kernel(const short* __restrict__ qkv,
                                                          short* __restrict__ vT) {
  __shared__ short tile[32][33];
  int n0 = blockIdx.x * 32, c0 = blockIdx.y * 32, b = blockIdx.z;
  int tx = threadIdx.x & 31, ty = threadIdx.x >> 5;
  for (int i = 0; i < 4; i++)
    tile[ty + i * 8][tx] = qkv[(size_t)(b * SEQ + n0 + ty + i * 8) * DQKV + 2560 + c0 + tx];
  __syncthreads();
  for (int i = 0; i < 4; i++)
    vT[(size_t)(b * 512 + c0 + ty + i * 8) * SEQ + n0 + tx] = tile[tx][ty + i * 8];
}

// ---------------- bf16 GEMM, BK=64: C[M][N] = A[M][K] @ BT[N][K]^T ----------------
// 128x128 macro-tile, BK=64 in two 32-k slabs (32KB LDS) -> half the barrier
// crossings of BK=32 while staying at the VGPR-bound 3 blocks/CU.
// F32OUT=0: cols<qcols scaled by qscale before bf16 cast (softmax scale into Q).
template <int F32OUT>
__global__ __launch_bounds__(256)
void gemm_bt_kernel(const short* __restrict__ A, const short* __restrict__ BT,
                    void* __restrict__ Cout, const float* __restrict__ bias,
                    int M, int N, int K, int qcols, float qscale) {
  __shared__ __align__(16) short As[8192];  // 2 kslabs x [128 rows][32 k]
  __shared__ __align__(16) short Bs[8192];
  const int tid = threadIdx.x, lane = tid & 63, w = tid >> 6;
  const int l15 = lane & 15, quad = lane >> 4, q8 = quad * 8;
  const int row0 = blockIdx.y * 128, col0 = blockIdx.x * 128;
  const int wm = (w >> 1) * 64, wn = (w & 1) * 64;
  f32x4 acc[4][4] = {};
  const short* ga0 = A  + (size_t)(row0 + w * 16 + (lane >> 2)) * K + (lane & 3) * 8;
  const short* gb0 = BT + (size_t)(col0 + w * 16 + (lane >> 2)) * K + (lane & 3) * 8;
  for (int kt = 0; kt < K; kt += 64) {
    for (int s = 0; s < 2; s++) {
      gl_lds16(ga0 + kt + s * 32,                  As + s * 4096 + w * 512);
      gl_lds16(ga0 + (size_t)64 * K + kt + s * 32, As + s * 4096 + 2048 + w * 512);
      gl_lds16(gb0 + kt + s * 32,                  Bs + s * 4096 + w * 512);
      gl_lds16(gb0 + (size_t)64 * K + kt + s * 32, Bs + s * 4096 + 2048 + w * 512);
    }
    __syncthreads();  // drains vmcnt -> staged tiles visible
    for (int s = 0; s < 2; s++) {
      bf16x8 af[4], bfr[4];
      for (int i = 0; i < 4; i++)
        af[i] = *reinterpret_cast<const bf16x8*>(As + s * 4096 + (wm + i * 16 + l15) * 32 + q8);
      for (int j = 0; j < 4; j++)
        bfr[j] = *reinterpret_cast<const bf16x8*>(Bs + s * 4096 + (wn + j * 16 + l15) * 32 + q8);
      for (int i = 0; i < 4; i++)
        for (int j = 0; j < 4; j++)
          acc[i][j] = __builtin_amdgcn_mfma_f32_16x16x32_bf16(af[i], bfr[j], acc[i][j], 0, 0, 0);
    }
    __syncthreads();  // protect LDS reuse next iteration
  }
  if (F32OUT) {
    float* C = (float*)Cout;
    for (int j = 0; j < 4; j++) {
      int col = col0 + wn + j * 16 + l15;
      float bv = bias[col];
      for (int i = 0; i < 4; i++)
        for (int r = 0; r < 4; r++)
          C[(size_t)(row0 + wm + i * 16 + quad * 4 + r) * N + col] = acc[i][j][r] + bv;
    }
  } else {
    short* C = (short*)Cout;
    for (int j = 0; j < 4; j++) {
      int col = col0 + wn + j * 16 + l15;
      float sc = (col < qcols) ? qscale : 1.0f;
      for (int i = 0; i < 4; i++)
        for (int r = 0; r < 4; r++)
          C[(size_t)(row0 + wm + i * 16 + quad * 4 + r) * N + col] = f2bf(acc[i][j][r] * sc);
    }
  }
}

// ---------------- flash attention, causal, GQA — 512 thr, 128-row Q tiles ----------
// grid: 512 blocks (16 qt x 16 h x 2 b), heavy-first. 8 waves/block share one K/V
// tile: waves 0-3 stage K, 4-7 stage V (staging per wave halved vs 256-thr version).
// K/V double-buffered, single barrier per iter. Ps: stride 64 with 16B XOR swizzle
// (chunk ^= l15&7) -> conflict-free reads, 2KB/wave. LDS = 32+32+16 = 80KB ->
// exactly 2 blocks/CU = 16 waves/CU. Q in regs, pre-scaled; no-max softmax;
// l via all-ones MFMA.
__global__ __launch_bounds__(512, 4)
void attn_kernel(const short* __restrict__ qkv, const short* __restrict__ vT,
                 short* __restrict__ ctx) {
  __shared__ __align__(16) short Ks[16384];  // 2 bufs x 4 dslabs x [64 k][32 d]
  __shared__ __align__(16) short Vs[16384];  // 2 bufs x 2 kslabs x [128 d][32 k]
  __shared__ __align__(16) short Ps[8192];   // 8 waves x [16 q][64 k] swizzled
  const int tid = threadIdx.x, lane = tid & 63, w = tid >> 6;  // w in 0..7
  const int l15 = lane & 15, quad = lane >> 4, q8 = quad * 8;
  const int idx = blockIdx.x;
  const int qt = 15 - (idx >> 5);          // heavy blocks dispatch first (LPT-ish)
  const int h = (idx >> 1) & 15, b = idx & 1, g = h >> 2;

  // Q rows for this wave in registers (16 q-rows x 128 d)
  bf16x8 qf[4];
  {
    const short* gq = qkv + (size_t)(b * SEQ + qt * 128 + w * 16 + l15) * DQKV + h * HD + q8;
    for (int ds = 0; ds < 4; ds++)
      qf[ds] = *reinterpret_cast<const bf16x8*>(gq + ds * 32);
  }
  bf16x8 ones;
  for (int i = 0; i < 8; i++) ones[i] = __builtin_bit_cast(__bf16, (short)0x3F80);

  f32x4 acco[8] = {};   // O^T: acco[nt][r] = O^T[d = nt*16+quad*4+r][q = l15]
  f32x4 accl = {};      // l (all 4 entries equal)

  // stage K/V tile kt into buffer buf: waves 0-3 stage K, waves 4-7 stage V
  auto stage = [&](int buf, int kt) {
    if (w < 4) {
      const short* gk = qkv + (size_t)(b * SEQ + kt * 64 + w * 16 + (lane >> 2)) * DQKV +
                        2048 + g * HD + (lane & 3) * 8;
      for (int ks = 0; ks < 4; ks++)
        gl_lds16(gk + ks * 32, Ks + buf * 8192 + ks * 2048 + w * 512);
    } else {
      const int w4 = w - 4;
      for (int c = 0; c < 2; c++)
        for (int ih = 0; ih < 2; ih++)
          gl_lds16(vT + (size_t)(b * 512 + g * HD + ih * 64 + w4 * 16 + (lane >> 2)) * SEQ +
                       kt * 64 + c * 32 + (lane & 3) * 8,
                   Vs + buf * 8192 + c * 4096 + ih * 2048 + w4 * 512);
    }
  };

  const int kmax = 2 * qt + 1;     // k-tiles 0..kmax (64 k each)
  stage(0, 0);
  for (int kt = 0; kt <= kmax; kt++) {
    const int cur = kt & 1;
    __syncthreads();                 // buf[cur] ready; all waves done with buf[cur^1]
    if (kt < kmax) stage(cur ^ 1, kt + 1);   // overlaps with ALL compute below

    const short* Kb = Ks + cur * 8192;
    const short* Vb = Vs + cur * 8192;

    // S^T = K @ Q^T : accs[j] rows k = j*16+quad*4+r, cols q = l15 (pre-scaled)
    f32x4 accs[4] = {};
    for (int ds = 0; ds < 4; ds++)
      for (int j = 0; j < 4; j++) {
        bf16x8 kf = *reinterpret_cast<const bf16x8*>(Kb + ds * 2048 + (j * 16 + l15) * 32 + q8);
        accs[j] = __builtin_amdgcn_mfma_f32_16x16x32_bf16(kf, qf[ds], accs[j], 0, 0, 0);
      }

    if (kt >= 2 * qt) {  // causal mask: only the last two k-tiles can cross the diagonal
      const int qm = qt * 128 + w * 16 + l15 - kt * 64;
      for (int j = 0; j < 4; j++)
        for (int r = 0; r < 4; r++)
          if (j * 16 + quad * 4 + r > qm) accs[j][r] = -1e38f;  // exp2 -> 0
    }

    // P = exp2(S); truncate-pack; swizzled per-lane write of P^T[k][q=l15]
    for (int j = 0; j < 4; j++) {
      float p0 = exp2f(accs[j][0]), p1 = exp2f(accs[j][1]);
      float p2 = exp2f(accs[j][2]), p3 = exp2f(accs[j][3]);
      unsigned u0 = __builtin_bit_cast(unsigned, p0), u1 = __builtin_bit_cast(unsigned, p1);
      unsigned u2 = __builtin_bit_cast(unsigned, p2), u3 = __builtin_bit_cast(unsigned, p3);
      uint2 dd = make_uint2((u0 >> 16) | (u1 & 0xffff0000u),
                            (u2 >> 16) | (u3 & 0xffff0000u));
      const int chw = (2 * j + (quad >> 1)) ^ (l15 & 7);  // 16B-chunk XOR swizzle
      *reinterpret_cast<uint2*>(Ps + w * 1024 + l15 * 64 + chw * 8 + (quad & 1) * 4) = dd;
    }
    // cross-lane P visibility within the wave (Ps region is wave-private)
    asm volatile("s_waitcnt lgkmcnt(0)" ::: "memory");

    // O^T += V^T @ P^T ; l += ones @ P^T (matrix pipe, zero VALU)
    for (int c = 0; c < 2; c++) {
      const int chr = (4 * c + quad) ^ (l15 & 7);
      bf16x8 pf = *reinterpret_cast<const bf16x8*>(Ps + w * 1024 + l15 * 64 + chr * 8);
      accl = __builtin_amdgcn_mfma_f32_16x16x32_bf16(ones, pf, accl, 0, 0, 0);
      for (int nt = 0; nt < 8; nt++) {
        bf16x8 vf = *reinterpret_cast<const bf16x8*>(Vb + c * 4096 + (nt * 16 + l15) * 32 + q8);
        acco[nt] = __builtin_amdgcn_mfma_f32_16x16x32_bf16(vf, pf, acco[nt], 0, 0, 0);
      }
    }
  }

  const float invl = 1.f / accl[0];
  const size_t row = (size_t)(b * SEQ + qt * 128 + w * 16 + l15);
  for (int nt = 0; nt < 8; nt++) {
    uint2 dd = make_uint2(pack2(acco[nt][0] * invl, acco[nt][1] * invl),
                          pack2(acco[nt][2] * invl, acco[nt][3] * invl));
    *reinterpret_cast<uint2*>(ctx + row * 2048 + h * HD + nt * 16 + quad * 4) = dd;
  }
}

extern "C" void kernel_launch(void* const* d_in, const int* in_sizes, int n_in,
                              void* d_out, int out_size, void* d_ws, size_t ws_size,
                              hipStream_t stream) {
  const float* x  = (const float*)d_in[0];
  const float* Wq = (const float*)d_in[1];
  const float* Wk = (const float*)d_in[2];
  const float* Wv = (const float*)d_in[3];
  const float* Wo = (const float*)d_in[4];
  const float* bo = (const float*)d_in[5];
  float* out = (float*)d_out;

  // softmax scale folded into Q: (1/sqrt(128)) * log2(e)
  const float sc2 = 0.08838834764831845f * 1.4426950408889634f;

  // workspace layout (bf16 as short), total ~84 MB
  short* xb    = (short*)d_ws;                   // [4096][2048]
  short* WqkvT = xb    + (size_t)4096 * 2048;    // [3072][2048]  rows: WqT | WkT | WvT
  short* WoT   = WqkvT + (size_t)3072 * 2048;    // [2048][2048]
  short* qkv   = WoT   + (size_t)2048 * 2048;    // [4096][3072]
  short* vT    = qkv   + (size_t)4096 * 3072;    // [2*512][2048]
  short* ctx   = vT    + (size_t)1024 * 2048;    // [4096][2048]

  prep_kernel<<<dim3(18432), dim3(256), 0, stream>>>(x, Wq, Wk, Wv, Wo, xb, WqkvT, WoT);
  // qkv = xb @ WqkvT^T : M=4096, N=3072, K=2048; q cols pre-scaled by sc2
  gemm_bt_kernel<0><<<dim3(24, 32), dim3(256), 0, stream>>>(xb, WqkvT, qkv, nullptr,
                                                            4096, 3072, 2048, 2048, sc2);
  transpose_v_kernel<<<dim3(64, 16, 2), dim3(256), 0, stream>>>(qkv, vT);
  attn_kernel<<<dim3(512), dim3(512), 0, stream>>>(qkv, vT, ctx);
  // out = ctx @ WoT^T + bo : M=4096, N=2048, K=2048, fp32 epilogue
  gemm_bt_kernel<1><<<dim3(16, 32), dim3(256), 0, stream>>>(ctx, WoT, out, bo,
                                                            4096, 2048, 2048, 0, 1.0f);
}

// Round 7
// 287.638 us; speedup vs baseline: 1.0641x; 1.0641x over previous
//
#include <hip/hip_runtime.h>
#include <stdint.h>

typedef __attribute__((ext_vector_type(8))) __bf16 bf16x8;
typedef __attribute__((ext_vector_type(4))) float f32x4;
typedef __attribute__((ext_vector_type(4))) short short4v;

// Problem constants
static constexpr int SEQ  = 2048;   // N
static constexpr int DQKV = 3072;   // q(2048) + k(512) + v(512)
static constexpr int HD   = 128;

// round-to-nearest-even fp32 -> bf16 bits
__device__ __forceinline__ short f2bf(float f) {
  unsigned u = __builtin_bit_cast(unsigned, f);
  u += 0x7fffu + ((u >> 16) & 1u);
  return (short)(u >> 16);
}

__device__ __forceinline__ unsigned pack2(float a, float b) {
  return (unsigned)(unsigned short)f2bf(a) | ((unsigned)(unsigned short)f2bf(b) << 16);
}

// async global->LDS, 16B per lane; LDS dest must be wave-uniform base + lane*16
__device__ __forceinline__ void gl_lds16(const void* g, void* l) {
  __builtin_amdgcn_global_load_lds(
      (const __attribute__((address_space(1))) void*)g,
      (__attribute__((address_space(3))) void*)l, 16, 0, 0);
}

// ---------------- fused prep: cast x + transpose-cast all weights ----------------
__global__ __launch_bounds__(256)
void prep_kernel(const float* __restrict__ x, const float* __restrict__ Wq,
                 const float* __restrict__ Wk, const float* __restrict__ Wv,
                 const float* __restrict__ Wo,
                 short* __restrict__ xb, short* __restrict__ WqkvT,
                 short* __restrict__ WoT) {
  int blk = blockIdx.x, tid = threadIdx.x;
  if (blk < 8192) {
    int i = blk * 256 + tid;
    float4 v = reinterpret_cast<const float4*>(x)[i];
    short4v o;
    o[0] = f2bf(v.x); o[1] = f2bf(v.y); o[2] = f2bf(v.z); o[3] = f2bf(v.w);
    *reinterpret_cast<short4v*>(xb + (size_t)i * 4) = o;
    return;
  }
  blk -= 8192;
  __shared__ float tile[32][33];
  const float* in; short* out; int C, bx, by;
  if (blk < 4096)      { in = Wq; out = WqkvT;                     C = 2048; bx = blk & 63; by = blk >> 6; }
  else if (blk < 5120) { int t = blk - 4096; in = Wk; out = WqkvT + (size_t)2048 * 2048; C = 512; bx = t & 15; by = t >> 4; }
  else if (blk < 6144) { int t = blk - 5120; in = Wv; out = WqkvT + (size_t)2560 * 2048; C = 512; bx = t & 15; by = t >> 4; }
  else                 { int t = blk - 6144; in = Wo; out = WoT;   C = 2048; bx = t & 63; by = t >> 6; }
  const int R = 2048;
  int c0 = bx * 32, r0 = by * 32, tx = tid & 31, ty = tid >> 5;
  for (int i = 0; i < 4; i++)
    tile[ty + i * 8][tx] = in[(size_t)(r0 + ty + i * 8) * C + c0 + tx];
  __syncthreads();
  for (int i = 0; i < 4; i++)
    out[(size_t)(c0 + ty + i * 8) * R + r0 + tx] = f2bf(tile[tx][ty + i * 8]);
}

// -------- transpose V section of qkv[4096][3072] -> vT[b*512 + gd][2048] bf16 --------
__global__ __launch_bounds__(256) void transpose_v_kernel(const short* __restrict__ qkv,
                                                          short* __restrict__ vT) {
  __shared__ short tile[32][33];
  int n0 = blockIdx.x * 32, c0 = blockIdx.y * 32, b = blockIdx.z;
  int tx = threadIdx.x & 31, ty = threadIdx.x >> 5;
  for (int i = 0; i < 4; i++)
    tile[ty + i * 8][tx] = qkv[(size_t)(b * SEQ + n0 + ty + i * 8) * DQKV + 2560 + c0 + tx];
  __syncthreads();
  for (int i = 0; i < 4; i++)
    vT[(size_t)(b * 512 + c0 + ty + i * 8) * SEQ + n0 + tx] = tile[tx][ty + i * 8];
}

// ---------------- bf16 GEMM, BK=64: C[M][N] = A[M][K] @ BT[N][K]^T ----------------
// 128x128 macro-tile, BK=64 in two 32-k slabs (32KB LDS) -> half the barrier
// crossings of BK=32 while staying at 3 blocks/CU (confirmed win R5->R6).
template <int F32OUT>
__global__ __launch_bounds__(256)
void gemm_bt_kernel(const short* __restrict__ A, const short* __restrict__ BT,
                    void* __restrict__ Cout, const float* __restrict__ bias,
                    int M, int N, int K, int qcols, float qscale) {
  __shared__ __align__(16) short As[8192];  // 2 kslabs x [128 rows][32 k]
  __shared__ __align__(16) short Bs[8192];
  const int tid = threadIdx.x, lane = tid & 63, w = tid >> 6;
  const int l15 = lane & 15, quad = lane >> 4, q8 = quad * 8;
  const int row0 = blockIdx.y * 128, col0 = blockIdx.x * 128;
  const int wm = (w >> 1) * 64, wn = (w & 1) * 64;
  f32x4 acc[4][4] = {};
  const short* ga0 = A  + (size_t)(row0 + w * 16 + (lane >> 2)) * K + (lane & 3) * 8;
  const short* gb0 = BT + (size_t)(col0 + w * 16 + (lane >> 2)) * K + (lane & 3) * 8;
  for (int kt = 0; kt < K; kt += 64) {
    for (int s = 0; s < 2; s++) {
      gl_lds16(ga0 + kt + s * 32,                  As + s * 4096 + w * 512);
      gl_lds16(ga0 + (size_t)64 * K + kt + s * 32, As + s * 4096 + 2048 + w * 512);
      gl_lds16(gb0 + kt + s * 32,                  Bs + s * 4096 + w * 512);
      gl_lds16(gb0 + (size_t)64 * K + kt + s * 32, Bs + s * 4096 + 2048 + w * 512);
    }
    __syncthreads();  // drains vmcnt -> staged tiles visible
    for (int s = 0; s < 2; s++) {
      bf16x8 af[4], bfr[4];
      for (int i = 0; i < 4; i++)
        af[i] = *reinterpret_cast<const bf16x8*>(As + s * 4096 + (wm + i * 16 + l15) * 32 + q8);
      for (int j = 0; j < 4; j++)
        bfr[j] = *reinterpret_cast<const bf16x8*>(Bs + s * 4096 + (wn + j * 16 + l15) * 32 + q8);
      for (int i = 0; i < 4; i++)
        for (int j = 0; j < 4; j++)
          acc[i][j] = __builtin_amdgcn_mfma_f32_16x16x32_bf16(af[i], bfr[j], acc[i][j], 0, 0, 0);
    }
    __syncthreads();  // protect LDS reuse next iteration
  }
  if (F32OUT) {
    float* C = (float*)Cout;
    for (int j = 0; j < 4; j++) {
      int col = col0 + wn + j * 16 + l15;
      float bv = bias[col];
      for (int i = 0; i < 4; i++)
        for (int r = 0; r < 4; r++)
          C[(size_t)(row0 + wm + i * 16 + quad * 4 + r) * N + col] = acc[i][j][r] + bv;
    }
  } else {
    short* C = (short*)Cout;
    for (int j = 0; j < 4; j++) {
      int col = col0 + wn + j * 16 + l15;
      float sc = (col < qcols) ? qscale : 1.0f;
      for (int i = 0; i < 4; i++)
        for (int r = 0; r < 4; r++)
          C[(size_t)(row0 + wm + i * 16 + quad * 4 + r) * N + col] = f2bf(acc[i][j][r] * sc);
    }
  }
}

// ---------------- flash attention, causal, GQA — paired-qt static balance ----------
// grid: 512 blocks x 256 thr. Block (p,h,b) processes qt = 31-p THEN qt = p:
// (32-p)+(p+1) = 33 k-iterations for EVERY block -> perfectly uniform work, all
// 512 blocks co-resident (73KB LDS -> 2 blocks/CU), zero tail. The K/V dbuf
// pipeline flows across the segment boundary (same b,g; only Q regs + acc switch).
// S^T formulation, no-max softmax (Q pre-scaled by (1/sqrt(HD))*log2(e) in the
// QKV-GEMM epilogue), l via all-ones MFMA, Ps stride-64 with 16B XOR swizzle.
__global__ __launch_bounds__(256, 2)
void attn_kernel(const short* __restrict__ qkv, const short* __restrict__ vT,
                 short* __restrict__ ctx) {
  __shared__ __align__(16) short Ks[16384];  // 2 bufs x 4 dslabs x [64 k][32 d]
  __shared__ __align__(16) short Vs[16384];  // 2 bufs x 2 kslabs x [128 d][32 k]
  __shared__ __align__(16) short Ps[4096];   // 4 waves x [16 q][64 k] swizzled
  const int tid = threadIdx.x, lane = tid & 63, w = tid >> 6;
  const int l15 = lane & 15, quad = lane >> 4, q8 = quad * 8;
  const int idx = blockIdx.x;
  const int p = idx >> 5, h = (idx >> 1) & 15, b = idx & 1, g = h >> 2;
  const int qtA = 31 - p, qtB = p;

  // both Q tiles for this wave in registers (2 x 16 q-rows x 128 d = 32 VGPRs)
  bf16x8 qf[2][4];
  for (int seg = 0; seg < 2; seg++) {
    const int qt = seg ? qtB : qtA;
    const short* gq = qkv + (size_t)(b * SEQ + qt * 64 + w * 16 + l15) * DQKV + h * HD + q8;
    for (int ds = 0; ds < 4; ds++)
      qf[seg][ds] = *reinterpret_cast<const bf16x8*>(gq + ds * 32);
  }
  bf16x8 ones;
  for (int i = 0; i < 8; i++) ones[i] = __builtin_bit_cast(__bf16, (short)0x3F80);

  f32x4 acco[8] = {};   // O^T: acco[nt][r] = O^T[d = nt*16+quad*4+r][q = l15]
  f32x4 accl = {};      // l (all 4 entries equal)

  auto stage = [&](int buf, int kt) {
    const short* gk = qkv + (size_t)(b * SEQ + kt * 64 + w * 16 + (lane >> 2)) * DQKV +
                      2048 + g * HD + (lane & 3) * 8;
    for (int ks = 0; ks < 4; ks++)
      gl_lds16(gk + ks * 32, Ks + buf * 8192 + ks * 2048 + w * 512);
    for (int c = 0; c < 2; c++)
      for (int ih = 0; ih < 2; ih++)
        gl_lds16(vT + (size_t)(b * 512 + g * HD + ih * 64 + w * 16 + (lane >> 2)) * SEQ +
                     kt * 64 + c * 32 + (lane & 3) * 8,
                 Vs + buf * 8192 + c * 4096 + ih * 2048 + w * 512);
  };

  const int lenA = qtA + 1;
  const int total = lenA + qtB + 1;   // == 33 for every block
  stage(0, 0);
  for (int t = 0; t < total; t++) {
    const int seg = (t >= lenA);
    const int kt = seg ? (t - lenA) : t;
    const int qt = seg ? qtB : qtA;
    const int cur = t & 1;
    __syncthreads();                 // buf[cur] ready; all waves done with buf[cur^1]
    if (t + 1 < total) {
      const int nkt = (t + 1 >= lenA) ? (t + 1 - lenA) : (t + 1);
      stage(cur ^ 1, nkt);           // overlaps with ALL compute below
    }

    const short* Kb = Ks + cur * 8192;
    const short* Vb = Vs + cur * 8192;

    // S^T = K @ Q^T : accs[j] rows k = j*16+quad*4+r, cols q = l15 (pre-scaled)
    f32x4 accs[4] = {};
    for (int ds = 0; ds < 4; ds++)
      for (int j = 0; j < 4; j++) {
        bf16x8 kf = *reinterpret_cast<const bf16x8*>(Kb + ds * 2048 + (j * 16 + l15) * 32 + q8);
        accs[j] = __builtin_amdgcn_mfma_f32_16x16x32_bf16(kf, qf[seg][ds], accs[j], 0, 0, 0);
      }

    if (kt == qt) {  // causal mask, diagonal tile only
      const int q = w * 16 + l15;
      for (int j = 0; j < 4; j++)
        for (int r = 0; r < 4; r++)
          if (j * 16 + quad * 4 + r > q) accs[j][r] = -1e38f;  // exp2 -> 0
    }

    // P = exp2(S); truncate-pack; swizzled per-lane write of P^T[k][q=l15]
    for (int j = 0; j < 4; j++) {
      float p0 = exp2f(accs[j][0]), p1 = exp2f(accs[j][1]);
      float p2 = exp2f(accs[j][2]), p3 = exp2f(accs[j][3]);
      unsigned u0 = __builtin_bit_cast(unsigned, p0), u1 = __builtin_bit_cast(unsigned, p1);
      unsigned u2 = __builtin_bit_cast(unsigned, p2), u3 = __builtin_bit_cast(unsigned, p3);
      uint2 dd = make_uint2((u0 >> 16) | (u1 & 0xffff0000u),
                            (u2 >> 16) | (u3 & 0xffff0000u));
      const int chw = (2 * j + (quad >> 1)) ^ (l15 & 7);  // 16B-chunk XOR swizzle
      *reinterpret_cast<uint2*>(Ps + w * 1024 + l15 * 64 + chw * 8 + (quad & 1) * 4) = dd;
    }
    // cross-lane P visibility within the wave (Ps region is wave-private)
    asm volatile("s_waitcnt lgkmcnt(0)" ::: "memory");

    // O^T += V^T @ P^T ; l += ones @ P^T (matrix pipe, zero VALU)
    for (int c = 0; c < 2; c++) {
      const int chr = (4 * c + quad) ^ (l15 & 7);
      bf16x8 pf = *reinterpret_cast<const bf16x8*>(Ps + w * 1024 + l15 * 64 + chr * 8);
      accl = __builtin_amdgcn_mfma_f32_16x16x32_bf16(ones, pf, accl, 0, 0, 0);
      for (int nt = 0; nt < 8; nt++) {
        bf16x8 vf = *reinterpret_cast<const bf16x8*>(Vb + c * 4096 + (nt * 16 + l15) * 32 + q8);
        acco[nt] = __builtin_amdgcn_mfma_f32_16x16x32_bf16(vf, pf, acco[nt], 0, 0, 0);
      }
    }

    if (kt == qt) {  // segment done: write O tile, reset accumulators
      const float invl = 1.f / accl[0];
      const size_t row = (size_t)(b * SEQ + qt * 64 + w * 16 + l15);
      for (int nt = 0; nt < 8; nt++) {
        uint2 dd = make_uint2(pack2(acco[nt][0] * invl, acco[nt][1] * invl),
                              pack2(acco[nt][2] * invl, acco[nt][3] * invl));
        *reinterpret_cast<uint2*>(ctx + row * 2048 + h * HD + nt * 16 + quad * 4) = dd;
      }
      for (int nt = 0; nt < 8; nt++) acco[nt] = f32x4{0.f, 0.f, 0.f, 0.f};
      accl = f32x4{0.f, 0.f, 0.f, 0.f};
    }
  }
}

extern "C" void kernel_launch(void* const* d_in, const int* in_sizes, int n_in,
                              void* d_out, int out_size, void* d_ws, size_t ws_size,
                              hipStream_t stream) {
  const float* x  = (const float*)d_in[0];
  const float* Wq = (const float*)d_in[1];
  const float* Wk = (const float*)d_in[2];
  const float* Wv = (const float*)d_in[3];
  const float* Wo = (const float*)d_in[4];
  const float* bo = (const float*)d_in[5];
  float* out = (float*)d_out;

  // softmax scale folded into Q: (1/sqrt(128)) * log2(e)
  const float sc2 = 0.08838834764831845f * 1.4426950408889634f;

  // workspace layout (bf16 as short), total ~84 MB
  short* xb    = (short*)d_ws;                   // [4096][2048]
  short* WqkvT = xb    + (size_t)4096 * 2048;    // [3072][2048]  rows: WqT | WkT | WvT
  short* WoT   = WqkvT + (size_t)3072 * 2048;    // [2048][2048]
  short* qkv   = WoT   + (size_t)2048 * 2048;    // [4096][3072]
  short* vT    = qkv   + (size_t)4096 * 3072;    // [2*512][2048]
  short* ctx   = vT    + (size_t)1024 * 2048;    // [4096][2048]

  prep_kernel<<<dim3(18432), dim3(256), 0, stream>>>(x, Wq, Wk, Wv, Wo, xb, WqkvT, WoT);
  // qkv = xb @ WqkvT^T : M=4096, N=3072, K=2048; q cols pre-scaled by sc2
  gemm_bt_kernel<0><<<dim3(24, 32), dim3(256), 0, stream>>>(xb, WqkvT, qkv, nullptr,
                                                            4096, 3072, 2048, 2048, sc2);
  transpose_v_kernel<<<dim3(64, 16, 2), dim3(256), 0, stream>>>(qkv, vT);
  attn_kernel<<<dim3(512), dim3(256), 0, stream>>>(qkv, vT, ctx);
  // out = ctx @ WoT^T + bo : M=4096, N=2048, K=2048, fp32 epilogue
  gemm_bt_kernel<1><<<dim3(16, 32), dim3(256), 0, stream>>>(ctx, WoT, out, bo,
                                                            4096, 2048, 2048, 0, 1.0f);
}